// Round 1
// baseline (245.987 us; speedup 1.0000x reference)
//
#include <hip/hip_runtime.h>
#include <math.h>

// Problem constants (fixed by the reference file)
#define NPOINTS   8192
#define NDIM      64
#define NTILES    128          // NPOINTS / 64
#define NPAIR_BLK 2048         // blocks for the B-term kernel

// ws float layout:
//  [0, 16384)        partA   : per-block partial sums of 1/(1+d2) over a<b
//  [16384, 18432)    a1p     : per-block partials of sum pij*(log pij + log s)
//  [18432, 20480)    a3p     : per-block partials of sum pij
//  [20480, 28672)    sq      : row squared norms
#define WS_PARTA 0
#define WS_A1P   16384
#define WS_A3P   18432
#define WS_SQ    20480

__global__ __launch_bounds__(256) void sq_kernel(const float* __restrict__ W,
                                                 float* __restrict__ sq) {
    int wid  = (blockIdx.x * 256 + threadIdx.x) >> 6;   // one wave per row
    int lane = threadIdx.x & 63;
    if (wid >= NPOINTS) return;
    float v = W[wid * NDIM + lane];
    v = v * v;
    #pragma unroll
    for (int m = 32; m >= 1; m >>= 1) v += __shfl_xor(v, m, 64);
    if (lane == 0) sq[wid] = v;
}

// 64x64 tile of the pairwise Cauchy sum per block; upper triangle only.
__global__ __launch_bounds__(256) void pairwise_kernel(const float* __restrict__ W,
                                                       const float* __restrict__ sq,
                                                       float* __restrict__ partA) {
    int bx = blockIdx.x, by = blockIdx.y;
    int bid = by * NTILES + bx;
    if (bx < by) {                      // lower triangle: contribute 0 (ws is poisoned!)
        if (threadIdx.x == 0) partA[bid] = 0.0f;
        return;
    }
    __shared__ float As[64][65];        // stride 65: conflict-free scalar reads
    __shared__ float Bs[64][65];
    __shared__ float wsum[4];

    int t  = threadIdx.x;
    int a0 = by * 64, b0 = bx * 64;

    // Stage both tiles: thread t loads 16 consecutive floats of row t/4.
    {
        int r  = t >> 2;
        int c0 = (t & 3) * 16;
        const float4* wa = (const float4*)(W + (a0 + r) * NDIM + c0);
        const float4* wb = (const float4*)(W + (b0 + r) * NDIM + c0);
        #pragma unroll
        for (int u = 0; u < 4; ++u) {
            float4 va = wa[u];
            float4 vb = wb[u];
            int c = c0 + 4 * u;
            As[r][c + 0] = va.x; As[r][c + 1] = va.y; As[r][c + 2] = va.z; As[r][c + 3] = va.w;
            Bs[r][c + 0] = vb.x; Bs[r][c + 1] = vb.y; Bs[r][c + 2] = vb.z; Bs[r][c + 3] = vb.w;
        }
    }
    __syncthreads();

    int ta = t >> 4;        // 0..15 -> 4 rows of A
    int tb = t & 15;        // 0..15 -> 4 rows of B
    float sqa[4], sqb[4];
    #pragma unroll
    for (int ia = 0; ia < 4; ++ia) sqa[ia] = sq[a0 + ta * 4 + ia];
    #pragma unroll
    for (int ib = 0; ib < 4; ++ib) sqb[ib] = sq[b0 + tb * 4 + ib];

    float dot[4][4] = {{0.f, 0.f, 0.f, 0.f}, {0.f, 0.f, 0.f, 0.f},
                       {0.f, 0.f, 0.f, 0.f}, {0.f, 0.f, 0.f, 0.f}};
    #pragma unroll 8
    for (int k = 0; k < NDIM; ++k) {
        float av[4], bv[4];
        #pragma unroll
        for (int ia = 0; ia < 4; ++ia) av[ia] = As[ta * 4 + ia][k];
        #pragma unroll
        for (int ib = 0; ib < 4; ++ib) bv[ib] = Bs[tb * 4 + ib][k];
        #pragma unroll
        for (int ia = 0; ia < 4; ++ia)
            #pragma unroll
            for (int ib = 0; ib < 4; ++ib)
                dot[ia][ib] = fmaf(av[ia], bv[ib], dot[ia][ib]);
    }

    bool diag = (bx == by);
    float ssum = 0.f;
    #pragma unroll
    for (int ia = 0; ia < 4; ++ia) {
        #pragma unroll
        for (int ib = 0; ib < 4; ++ib) {
            float d2 = sqa[ia] + sqb[ib] - 2.0f * dot[ia][ib];
            d2 = fmaxf(d2, 0.0f);
            float inv = __builtin_amdgcn_rcpf(1.0f + d2);
            // strictly-upper pairs only (diagonal tile masks b<=a; off-diag all valid)
            bool take = !diag || ((tb * 4 + ib) > (ta * 4 + ia));
            ssum += take ? inv : 0.0f;
        }
    }
    #pragma unroll
    for (int m = 32; m >= 1; m >>= 1) ssum += __shfl_xor(ssum, m, 64);
    if ((t & 63) == 0) wsum[t >> 6] = ssum;
    __syncthreads();
    if (t == 0) partA[bid] = wsum[0] + wsum[1] + wsum[2] + wsum[3];
}

// One wave per sampled (i,j) pair: lane = dim, coalesced 256B row reads.
__global__ __launch_bounds__(256) void pair_kernel(const float* __restrict__ W,
                                                   const float* __restrict__ pij,
                                                   const int* __restrict__ ii,
                                                   const int* __restrict__ jj,
                                                   int nb,
                                                   float* __restrict__ a1p,
                                                   float* __restrict__ a3p) {
    int wid   = (blockIdx.x * 256 + threadIdx.x) >> 6;
    int lane  = threadIdx.x & 63;
    int nwave = (gridDim.x * 256) >> 6;
    __shared__ float s1[4], s3[4];

    float a1 = 0.f, a3 = 0.f;
    for (int p = wid; p < nb; p += nwave) {
        int   i  = ii[p];             // wave-uniform -> scalar loads
        int   j  = jj[p];
        float pv = pij[p];
        float d  = W[i * NDIM + lane] - W[j * NDIM + lane];
        float v  = d * d;
        #pragma unroll
        for (int m = 32; m >= 1; m >>= 1) v += __shfl_xor(v, m, 64);
        // v == ||xi-xj||^2 on every lane; s = n_topics + d2 (faithful "+1 per dim")
        a1 = fmaf(pv, __logf(pv) + __logf((float)NDIM + v), a1);
        a3 += pv;
    }
    if (lane == 0) { s1[threadIdx.x >> 6] = a1; s3[threadIdx.x >> 6] = a3; }
    __syncthreads();
    if (threadIdx.x == 0) {
        a1p[blockIdx.x] = s1[0] + s1[1] + s1[2] + s1[3];
        a3p[blockIdx.x] = s3[0] + s3[1] + s3[2] + s3[3];
    }
}

__global__ __launch_bounds__(256) void final_kernel(const float* __restrict__ partA,
                                                    const float* __restrict__ a1p,
                                                    const float* __restrict__ a3p,
                                                    float* __restrict__ out) {
    __shared__ double r1[256], r2[256], r3[256];
    int t = threadIdx.x;
    double dpart = 0.0, d1 = 0.0, d3 = 0.0;
    for (int k = t; k < NTILES * NTILES; k += 256) dpart += (double)partA[k];
    for (int k = t; k < NPAIR_BLK; k += 256) { d1 += (double)a1p[k]; d3 += (double)a3p[k]; }
    r1[t] = dpart; r2[t] = d1; r3[t] = d3;
    __syncthreads();
    for (int s = 128; s >= 1; s >>= 1) {
        if (t < s) { r1[t] += r1[t + s]; r2[t] += r2[t + s]; r3[t] += r3[t + s]; }
        __syncthreads();
    }
    if (t == 0) {
        double part = 2.0 * r1[0];                 // sum over a<b, doubled; diagonal cancels -n
        out[0] = (float)(r2[0] + r3[0] * log(part));
    }
}

extern "C" void kernel_launch(void* const* d_in, const int* in_sizes, int n_in,
                              void* d_out, int out_size, void* d_ws, size_t ws_size,
                              hipStream_t stream) {
    const float* pij = (const float*)d_in[0];
    const int*   ii  = (const int*)d_in[1];
    const int*   jj  = (const int*)d_in[2];
    const float* W   = (const float*)d_in[3];
    float* out = (float*)d_out;
    float* ws  = (float*)d_ws;

    float* partA = ws + WS_PARTA;
    float* a1p   = ws + WS_A1P;
    float* a3p   = ws + WS_A3P;
    float* sqv   = ws + WS_SQ;

    int nb = in_sizes[0];   // number of sampled pairs (B)

    sq_kernel<<<NPOINTS / 4, 256, 0, stream>>>(W, sqv);
    pairwise_kernel<<<dim3(NTILES, NTILES), 256, 0, stream>>>(W, sqv, partA);
    pair_kernel<<<NPAIR_BLK, 256, 0, stream>>>(W, pij, ii, jj, nb, a1p, a3p);
    final_kernel<<<1, 256, 0, stream>>>(partA, a1p, a3p, out);
}

// Round 2
// 128.254 us; speedup vs baseline: 1.9180x; 1.9180x over previous
//
#include <hip/hip_runtime.h>
#include <math.h>

// Problem constants (fixed by the reference file)
#define NPOINTS   8192
#define NDIM      64
#define TILE      128          // pairwise output tile per block
#define NT2       64           // NPOINTS / TILE
#define NPAIR_BLK 2048         // blocks for the B-term kernel

// ws float layout:
//  [0, 4096)      partA : per-block partial sums of 1/(1+d2) over a<b   (64x64 grid)
//  [4096, 6144)   a1p   : per-block partials of sum pij*(log pij + log s)
//  [6144, 8192)   a3p   : per-block partials of sum pij
//  [8192, 16384)  sq    : row squared norms (fp32 exact)
#define WS_PARTA 0
#define WS_A1P   4096
#define WS_A3P   6144
#define WS_SQ    8192

typedef __attribute__((ext_vector_type(8))) short bf16x8;   // 8 bf16 = 4 VGPRs (MFMA A/B frag)
typedef __attribute__((ext_vector_type(4))) float f32x4;    // MFMA C/D frag

__device__ inline unsigned short f2bf(float f) {            // fp32 -> bf16 RNE
    unsigned u = __float_as_uint(f);
    u += 0x7FFFu + ((u >> 16) & 1u);
    return (unsigned short)(u >> 16);
}

__global__ __launch_bounds__(256) void sq_kernel(const float* __restrict__ W,
                                                 float* __restrict__ sq) {
    int wid  = (blockIdx.x * 256 + threadIdx.x) >> 6;   // one wave per row
    int lane = threadIdx.x & 63;
    if (wid >= NPOINTS) return;
    float v = W[wid * NDIM + lane];
    v = v * v;
    #pragma unroll
    for (int m = 32; m >= 1; m >>= 1) v += __shfl_xor(v, m, 64);
    if (lane == 0) sq[wid] = v;
}

// 128x128 tile of the pairwise Cauchy sum per block via bf16 MFMA; upper triangle only.
// Layouts (HW-verified, see guide §3): A/B frag = X[idx=lane&15][k=(lane>>4)*8+j],
// C/D = D[row=(lane>>4)*4+reg][col=lane&15].
__global__ __launch_bounds__(256) void pairwise_kernel(const float* __restrict__ W,
                                                       const float* __restrict__ sq,
                                                       float* __restrict__ partA) {
    int bx = blockIdx.x, by = blockIdx.y;
    int bid = by * NT2 + bx;
    if (bx < by) {                      // lower triangle: contribute 0 (ws is poisoned!)
        if (threadIdx.x == 0) partA[bid] = 0.0f;
        return;
    }
    // rows padded to 72 bf16 (144 B): b128 frag reads alias 2-way max (free)
    __shared__ __align__(16) unsigned short Abuf[TILE * 72];
    __shared__ __align__(16) unsigned short Bbuf[TILE * 72];
    __shared__ float sqAs[TILE];
    __shared__ float sqBs[TILE];
    __shared__ float wsum[4];

    int t  = threadIdx.x;
    int a0 = by * TILE, b0 = bx * TILE;

    // ---- stage: fp32 W rows -> bf16 LDS tiles (thread t: row t/2, 32-col half t&1)
    {
        int r  = t >> 1;
        int h2 = t & 1;
        const float4* rowA = (const float4*)(W + (a0 + r) * NDIM + h2 * 32);
        const float4* rowB = (const float4*)(W + (b0 + r) * NDIM + h2 * 32);
        unsigned short* da = &Abuf[r * 72 + h2 * 32];
        unsigned short* db = &Bbuf[r * 72 + h2 * 32];
        #pragma unroll
        for (int u = 0; u < 4; ++u) {
            float4 a0v = rowA[2 * u], a1v = rowA[2 * u + 1];
            float4 b0v = rowB[2 * u], b1v = rowB[2 * u + 1];
            bf16x8 pa, pb;
            pa[0] = f2bf(a0v.x); pa[1] = f2bf(a0v.y); pa[2] = f2bf(a0v.z); pa[3] = f2bf(a0v.w);
            pa[4] = f2bf(a1v.x); pa[5] = f2bf(a1v.y); pa[6] = f2bf(a1v.z); pa[7] = f2bf(a1v.w);
            pb[0] = f2bf(b0v.x); pb[1] = f2bf(b0v.y); pb[2] = f2bf(b0v.z); pb[3] = f2bf(b0v.w);
            pb[4] = f2bf(b1v.x); pb[5] = f2bf(b1v.y); pb[6] = f2bf(b1v.z); pb[7] = f2bf(b1v.w);
            *(bf16x8*)(da + u * 8) = pa;
            *(bf16x8*)(db + u * 8) = pb;
        }
        if (t < TILE) sqAs[t] = sq[a0 + t];
        else          sqBs[t - TILE] = sq[b0 + (t - TILE)];
    }
    __syncthreads();

    // ---- compute: each wave owns a 64x64 quadrant (wm,wn), 4x4 MFMA tiles, K=64
    int w    = t >> 6;
    int lane = t & 63;
    int wm   = w >> 1, wn = w & 1;
    int quad = lane >> 4, l15 = lane & 15;

    f32x4 acc[4][4];
    #pragma unroll
    for (int i = 0; i < 4; ++i)
        #pragma unroll
        for (int j = 0; j < 4; ++j) acc[i][j] = (f32x4){0.f, 0.f, 0.f, 0.f};

    #pragma unroll
    for (int h = 0; h < 2; ++h) {       // two K=32 halves
        bf16x8 af[4], bfr[4];
        #pragma unroll
        for (int tm = 0; tm < 4; ++tm)
            af[tm] = *(const bf16x8*)(&Abuf[(wm * 64 + tm * 16 + l15) * 72 + h * 32 + quad * 8]);
        #pragma unroll
        for (int tn = 0; tn < 4; ++tn)
            bfr[tn] = *(const bf16x8*)(&Bbuf[(wn * 64 + tn * 16 + l15) * 72 + h * 32 + quad * 8]);
        #pragma unroll
        for (int tm = 0; tm < 4; ++tm)
            #pragma unroll
            for (int tn = 0; tn < 4; ++tn)
                acc[tm][tn] = __builtin_amdgcn_mfma_f32_16x16x32_bf16(af[tm], bfr[tn],
                                                                      acc[tm][tn], 0, 0, 0);
    }

    // ---- epilogue: d2 = sqa + sqb - 2*dot; sum 1/(1+d2) over valid (a<b) pairs
    bool offdiag = (bx > by);
    float ssum = 0.f;
    #pragma unroll
    for (int tn = 0; tn < 4; ++tn) {
        int cl = wn * 64 + tn * 16 + l15;           // local col in [0,128)
        float sqb = sqBs[cl];
        #pragma unroll
        for (int tm = 0; tm < 4; ++tm) {
            #pragma unroll
            for (int r = 0; r < 4; ++r) {
                int rl = wm * 64 + tm * 16 + quad * 4 + r;   // local row in [0,128)
                float d2 = fmaxf(sqAs[rl] + sqb - 2.0f * acc[tm][tn][r], 0.0f);
                float inv = __builtin_amdgcn_rcpf(1.0f + d2);
                bool take = offdiag || (cl > rl);
                ssum += take ? inv : 0.0f;
            }
        }
    }
    #pragma unroll
    for (int m = 32; m >= 1; m >>= 1) ssum += __shfl_xor(ssum, m, 64);
    if (lane == 0) wsum[w] = ssum;
    __syncthreads();
    if (t == 0) partA[bid] = wsum[0] + wsum[1] + wsum[2] + wsum[3];
}

// 16 lanes per sampled pair (4 pairs/wave): float4/lane row gathers, 4-step reduce.
__global__ __launch_bounds__(256) void pair_kernel(const float* __restrict__ W,
                                                   const float* __restrict__ pij,
                                                   const int* __restrict__ ii,
                                                   const int* __restrict__ jj,
                                                   int nb,
                                                   float* __restrict__ a1p,
                                                   float* __restrict__ a3p) {
    int t    = threadIdx.x;
    int lane = t & 63;
    int g    = lane >> 4;          // pair slot within wave (0..3)
    int s    = lane & 15;          // element slot (4 floats each)
    int wid  = (blockIdx.x * 256 + t) >> 6;
    int nwave = NPAIR_BLK * 4;
    __shared__ float s1[4], s3[4];

    float a1 = 0.f, a3 = 0.f;
    for (int p0 = wid * 4; p0 < nb; p0 += nwave * 4) {
        int  p  = p0 + g;
        bool ok = p < nb;
        int  pc = ok ? p : 0;
        int   i  = ii[pc];
        int   j  = jj[pc];
        float pv = pij[pc];
        float4 xi = *(const float4*)(W + i * NDIM + s * 4);
        float4 xj = *(const float4*)(W + j * NDIM + s * 4);
        float dx = xi.x - xj.x, dy = xi.y - xj.y, dz = xi.z - xj.z, dw = xi.w - xj.w;
        float v = dx * dx;
        v = fmaf(dy, dy, v);
        v = fmaf(dz, dz, v);
        v = fmaf(dw, dw, v);
        v += __shfl_xor(v, 1, 64);
        v += __shfl_xor(v, 2, 64);
        v += __shfl_xor(v, 4, 64);
        v += __shfl_xor(v, 8, 64);      // all 16 lanes of the group now hold ||xi-xj||^2
        float term = pv * (__logf(pv) + __logf((float)NDIM + v));
        a1 += ok ? term : 0.f;          //每 pair counted 16x -> scaled by 1/16 below
        a3 += ok ? pv : 0.f;
    }
    #pragma unroll
    for (int m = 32; m >= 1; m >>= 1) {
        a1 += __shfl_xor(a1, m, 64);
        a3 += __shfl_xor(a3, m, 64);
    }
    if (lane == 0) { s1[t >> 6] = a1 * 0.0625f; s3[t >> 6] = a3 * 0.0625f; }
    __syncthreads();
    if (t == 0) {
        a1p[blockIdx.x] = s1[0] + s1[1] + s1[2] + s1[3];
        a3p[blockIdx.x] = s3[0] + s3[1] + s3[2] + s3[3];
    }
}

__global__ __launch_bounds__(256) void final_kernel(const float* __restrict__ partA,
                                                    const float* __restrict__ a1p,
                                                    const float* __restrict__ a3p,
                                                    float* __restrict__ out) {
    __shared__ double r1[256], r2[256], r3[256];
    int t = threadIdx.x;
    double dpart = 0.0, d1 = 0.0, d3 = 0.0;
    for (int k = t; k < NT2 * NT2; k += 256) dpart += (double)partA[k];
    for (int k = t; k < NPAIR_BLK; k += 256) { d1 += (double)a1p[k]; d3 += (double)a3p[k]; }
    r1[t] = dpart; r2[t] = d1; r3[t] = d3;
    __syncthreads();
    for (int s = 128; s >= 1; s >>= 1) {
        if (t < s) { r1[t] += r1[t + s]; r2[t] += r2[t + s]; r3[t] += r3[t + s]; }
        __syncthreads();
    }
    if (t == 0) {
        double part = 2.0 * r1[0];                 // sum over a<b, doubled; diagonal cancels -n
        out[0] = (float)(r2[0] + r3[0] * log(part));
    }
}

extern "C" void kernel_launch(void* const* d_in, const int* in_sizes, int n_in,
                              void* d_out, int out_size, void* d_ws, size_t ws_size,
                              hipStream_t stream) {
    const float* pij = (const float*)d_in[0];
    const int*   ii  = (const int*)d_in[1];
    const int*   jj  = (const int*)d_in[2];
    const float* W   = (const float*)d_in[3];
    float* out = (float*)d_out;
    float* ws  = (float*)d_ws;

    float* partA = ws + WS_PARTA;
    float* a1p   = ws + WS_A1P;
    float* a3p   = ws + WS_A3P;
    float* sqv   = ws + WS_SQ;

    int nb = in_sizes[0];   // number of sampled pairs (B)

    sq_kernel<<<NPOINTS / 4, 256, 0, stream>>>(W, sqv);
    pairwise_kernel<<<dim3(NT2, NT2), 256, 0, stream>>>(W, sqv, partA);
    pair_kernel<<<NPAIR_BLK, 256, 0, stream>>>(W, pij, ii, jj, nb, a1p, a3p);
    final_kernel<<<1, 256, 0, stream>>>(partA, a1p, a3p, out);
}

// Round 3
// 103.063 us; speedup vs baseline: 2.3868x; 1.2444x over previous
//
#include <hip/hip_runtime.h>
#include <math.h>

// Problem constants (fixed by the reference file)
#define NPOINTS   8192
#define NDIM      64
#define TILE      128          // pairwise output tile per block
#define NT2       64           // NPOINTS / TILE
#define NBLK      2080         // NT2*(NT2+1)/2 triangle blocks
#define NPAIR_BLK 2048         // blocks for the B-term kernel

// ws float/dword layout:
//  [0, 262144)        W16   : W converted to bf16, packed 2/dword (8192 rows x 32 dwords)
//  [262144, 270336)   sq    : row squared norms (fp32 exact)
//  [270336, 272416)   partA : per-block partials of sum 1/(1+d2) over a<b  (2080)
//  [272416, 274464)   a1p   : per-block partials of sum pij*(log pij + log s)
//  [274464, 276512)   a3p   : per-block partials of sum pij
#define WS_W16   0
#define WS_SQ    262144
#define WS_PARTA 270336
#define WS_A1P   272416
#define WS_A3P   274464

typedef __attribute__((ext_vector_type(8))) short bf16x8;   // 8 bf16 = 4 VGPRs (MFMA A/B frag)
typedef __attribute__((ext_vector_type(4))) float f32x4;    // MFMA C/D frag

__device__ inline unsigned short f2bf(float f) {            // fp32 -> bf16 RNE
    unsigned u = __float_as_uint(f);
    u += 0x7FFFu + ((u >> 16) & 1u);
    return (unsigned short)(u >> 16);
}
__device__ inline float bflo(unsigned u) { return __uint_as_float(u << 16); }
__device__ inline float bfhi(unsigned u) { return __uint_as_float(u & 0xFFFF0000u); }

// One wave per row: exact fp32 row norm + bf16 conversion of W (packed 2/dword).
__global__ __launch_bounds__(256) void prep_kernel(const float* __restrict__ W,
                                                   float* __restrict__ sq,
                                                   unsigned* __restrict__ W16) {
    int wid  = (blockIdx.x * 256 + threadIdx.x) >> 6;   // row
    int lane = threadIdx.x & 63;
    float v = W[wid * NDIM + lane];
    float s = v * v;
    #pragma unroll
    for (int m = 32; m >= 1; m >>= 1) s += __shfl_xor(s, m, 64);
    if (lane == 0) sq[wid] = s;
    unsigned bf   = f2bf(v);
    unsigned peer = (unsigned)__shfl_xor((int)bf, 1, 64);
    if ((lane & 1) == 0)                                 // even lane packs (elem l | elem l+1)
        W16[wid * 32 + (lane >> 1)] = (bf & 0xFFFFu) | (peer << 16);
}

// 128x128 tile of the pairwise Cauchy sum; 1D triangle grid; fragments loaded
// DIRECTLY from global bf16 (no LDS staging, no mid-kernel barrier).
// Frag layouts (HW-verified): A/B = X[idx=lane&15][k=(lane>>4)*8+j]; C/D row=(lane>>4)*4+reg, col=lane&15.
__global__ __launch_bounds__(256) void pairwise_kernel(const unsigned* __restrict__ W16,
                                                       const float* __restrict__ sq,
                                                       float* __restrict__ partA) {
    int z = blockIdx.x;
    // decode (by,bx) with bx>=by from linear triangle index
    int by = (int)((129.0 - sqrt(16641.0 - 8.0 * (double)z)) * 0.5);
    while (by * NT2 - by * (by - 1) / 2 > z) --by;
    while ((by + 1) * NT2 - (by + 1) * by / 2 <= z) ++by;
    int bx = by + (z - (by * NT2 - by * (by - 1) / 2));

    int t = threadIdx.x, w = t >> 6, lane = t & 63;
    int wm = w >> 1, wn = w & 1, quad = lane >> 4, l15 = lane & 15;
    int a0 = by * TILE, b0 = bx * TILE;

    // sq prefetch (independent of MFMA stream; issued early)
    float base1[4][4], sqb[4];
    {
        int arow = a0 + wm * 64 + quad * 4;
        #pragma unroll
        for (int tm = 0; tm < 4; ++tm)
            #pragma unroll
            for (int r = 0; r < 4; ++r) base1[tm][r] = 1.0f + sq[arow + tm * 16 + r];
        int bcol = b0 + wn * 64 + l15;
        #pragma unroll
        for (int tn = 0; tn < 4; ++tn) sqb[tn] = sq[bcol + tn * 16];
    }

    f32x4 acc[4][4];
    #pragma unroll
    for (int i = 0; i < 4; ++i)
        #pragma unroll
        for (int j = 0; j < 4; ++j) acc[i][j] = (f32x4){0.f, 0.f, 0.f, 0.f};

    const unsigned* Arow = W16 + (a0 + wm * 64 + l15) * 32;   // row pitch 32 dwords
    const unsigned* Brow = W16 + (b0 + wn * 64 + l15) * 32;
    #pragma unroll
    for (int h = 0; h < 2; ++h) {       // two K=32 halves; frag = 4 dwords, 16B-aligned
        bf16x8 af[4], bfr[4];
        #pragma unroll
        for (int tm = 0; tm < 4; ++tm)
            af[tm] = *(const bf16x8*)(Arow + tm * 16 * 32 + h * 16 + quad * 4);
        #pragma unroll
        for (int tn = 0; tn < 4; ++tn)
            bfr[tn] = *(const bf16x8*)(Brow + tn * 16 * 32 + h * 16 + quad * 4);
        #pragma unroll
        for (int tm = 0; tm < 4; ++tm)
            #pragma unroll
            for (int tn = 0; tn < 4; ++tn)
                acc[tm][tn] = __builtin_amdgcn_mfma_f32_16x16x32_bf16(af[tm], bfr[tn],
                                                                      acc[tm][tn], 0, 0, 0);
    }

    // epilogue: 1+d2 = (1+sqa+sqb) - 2*dot ; no clamp needed (>= ~0.9 even with bf16 error)
    float ssum = 0.f;
    if (bx > by) {
        #pragma unroll
        for (int tn = 0; tn < 4; ++tn)
            #pragma unroll
            for (int tm = 0; tm < 4; ++tm)
                #pragma unroll
                for (int r = 0; r < 4; ++r) {
                    float c = base1[tm][r] + sqb[tn];
                    ssum += __builtin_amdgcn_rcpf(fmaf(acc[tm][tn][r], -2.0f, c));
                }
    } else {                             // diagonal block: strictly-upper only
        #pragma unroll
        for (int tn = 0; tn < 4; ++tn) {
            int cl = wn * 64 + tn * 16 + l15;
            #pragma unroll
            for (int tm = 0; tm < 4; ++tm)
                #pragma unroll
                for (int r = 0; r < 4; ++r) {
                    int rl = wm * 64 + tm * 16 + quad * 4 + r;
                    float c = base1[tm][r] + sqb[tn];
                    float inv = __builtin_amdgcn_rcpf(fmaf(acc[tm][tn][r], -2.0f, c));
                    ssum += (cl > rl) ? inv : 0.f;
                }
        }
    }
    #pragma unroll
    for (int m = 32; m >= 1; m >>= 1) ssum += __shfl_xor(ssum, m, 64);
    __shared__ float wsum[4];
    if (lane == 0) wsum[w] = ssum;
    __syncthreads();
    if (t == 0) partA[z] = wsum[0] + wsum[1] + wsum[2] + wsum[3];
}

// 8 lanes per pair, two independent pair-sets per iteration (ILP), bf16 gathers,
// single fused log: pij*(log pij + log(64+d2)) = pij*log(pij*(64+d2)).
__global__ __launch_bounds__(256) void pair_kernel(const unsigned* __restrict__ W16,
                                                   const float* __restrict__ pij,
                                                   const int* __restrict__ ii,
                                                   const int* __restrict__ jj,
                                                   int nb,
                                                   float* __restrict__ a1p,
                                                   float* __restrict__ a3p) {
    int t = threadIdx.x, lane = t & 63;
    int g = lane >> 3;             // pair slot (0..7)
    int s = lane & 7;              // 8 bf16 (16B) per lane slot
    int wid = (blockIdx.x * 256 + t) >> 6;
    const int nwave = NPAIR_BLK * 4;
    __shared__ float s1[4], s3[4];

    float a1 = 0.f, a3 = 0.f;
    for (int p0 = wid * 16; p0 < nb; p0 += nwave * 16) {
        int  pA = p0 + g,          pB = p0 + 8 + g;
        bool okA = pA < nb,        okB = pB < nb;
        int  cA = okA ? pA : 0,    cB = okB ? pB : 0;
        int   iA = ii[cA], jA = jj[cA];
        int   iB = ii[cB], jB = jj[cB];
        float pvA = pij[cA], pvB = pij[cB];
        uint4 xiA = *(const uint4*)(W16 + iA * 32 + s * 4);
        uint4 xjA = *(const uint4*)(W16 + jA * 32 + s * 4);
        uint4 xiB = *(const uint4*)(W16 + iB * 32 + s * 4);
        uint4 xjB = *(const uint4*)(W16 + jB * 32 + s * 4);

        float vA, vB;
        {
            float d0 = bflo(xiA.x) - bflo(xjA.x), d1 = bfhi(xiA.x) - bfhi(xjA.x);
            float d2 = bflo(xiA.y) - bflo(xjA.y), d3 = bfhi(xiA.y) - bfhi(xjA.y);
            float d4 = bflo(xiA.z) - bflo(xjA.z), d5 = bfhi(xiA.z) - bfhi(xjA.z);
            float d6 = bflo(xiA.w) - bflo(xjA.w), d7 = bfhi(xiA.w) - bfhi(xjA.w);
            vA = d0 * d0;
            vA = fmaf(d1, d1, vA); vA = fmaf(d2, d2, vA); vA = fmaf(d3, d3, vA);
            vA = fmaf(d4, d4, vA); vA = fmaf(d5, d5, vA); vA = fmaf(d6, d6, vA);
            vA = fmaf(d7, d7, vA);
        }
        {
            float d0 = bflo(xiB.x) - bflo(xjB.x), d1 = bfhi(xiB.x) - bfhi(xjB.x);
            float d2 = bflo(xiB.y) - bflo(xjB.y), d3 = bfhi(xiB.y) - bfhi(xjB.y);
            float d4 = bflo(xiB.z) - bflo(xjB.z), d5 = bfhi(xiB.z) - bfhi(xjB.z);
            float d6 = bflo(xiB.w) - bflo(xjB.w), d7 = bfhi(xiB.w) - bfhi(xjB.w);
            vB = d0 * d0;
            vB = fmaf(d1, d1, vB); vB = fmaf(d2, d2, vB); vB = fmaf(d3, d3, vB);
            vB = fmaf(d4, d4, vB); vB = fmaf(d5, d5, vB); vB = fmaf(d7, d7, fmaf(d6, d6, vB));
        }
        #pragma unroll
        for (int m = 1; m <= 4; m <<= 1) {
            vA += __shfl_xor(vA, m, 64);
            vB += __shfl_xor(vB, m, 64);
        }
        float tA = pvA * __logf(pvA * ((float)NDIM + vA));
        float tB = pvB * __logf(pvB * ((float)NDIM + vB));
        a1 += okA ? tA : 0.f;  a3 += okA ? pvA : 0.f;
        a1 += okB ? tB : 0.f;  a3 += okB ? pvB : 0.f;
    }
    #pragma unroll
    for (int m = 32; m >= 1; m >>= 1) {
        a1 += __shfl_xor(a1, m, 64);
        a3 += __shfl_xor(a3, m, 64);
    }
    if (lane == 0) { s1[t >> 6] = a1 * 0.125f; s3[t >> 6] = a3 * 0.125f; }  // 8x lane redundancy
    __syncthreads();
    if (t == 0) {
        a1p[blockIdx.x] = s1[0] + s1[1] + s1[2] + s1[3];
        a3p[blockIdx.x] = s3[0] + s3[1] + s3[2] + s3[3];
    }
}

__global__ __launch_bounds__(256) void final_kernel(const float* __restrict__ partA,
                                                    const float* __restrict__ a1p,
                                                    const float* __restrict__ a3p,
                                                    float* __restrict__ out) {
    __shared__ double r1[256], r2[256], r3[256];
    int t = threadIdx.x;
    double dpart = 0.0, d1 = 0.0, d3 = 0.0;
    for (int k = t; k < NBLK; k += 256) dpart += (double)partA[k];
    for (int k = t; k < NPAIR_BLK; k += 256) { d1 += (double)a1p[k]; d3 += (double)a3p[k]; }
    r1[t] = dpart; r2[t] = d1; r3[t] = d3;
    __syncthreads();
    for (int s = 128; s >= 1; s >>= 1) {
        if (t < s) { r1[t] += r1[t + s]; r2[t] += r2[t + s]; r3[t] += r3[t + s]; }
        __syncthreads();
    }
    if (t == 0) {
        double part = 2.0 * r1[0];                 // sum over a<b, doubled; diagonal cancels -n
        out[0] = (float)(r2[0] + r3[0] * log(part));
    }
}

extern "C" void kernel_launch(void* const* d_in, const int* in_sizes, int n_in,
                              void* d_out, int out_size, void* d_ws, size_t ws_size,
                              hipStream_t stream) {
    const float* pij = (const float*)d_in[0];
    const int*   ii  = (const int*)d_in[1];
    const int*   jj  = (const int*)d_in[2];
    const float* W   = (const float*)d_in[3];
    float* out = (float*)d_out;
    float* ws  = (float*)d_ws;

    unsigned* W16  = (unsigned*)ws + WS_W16;
    float*    sqv  = ws + WS_SQ;
    float*    partA = ws + WS_PARTA;
    float*    a1p  = ws + WS_A1P;
    float*    a3p  = ws + WS_A3P;

    int nb = in_sizes[0];   // number of sampled pairs (B)

    prep_kernel<<<NPOINTS / 4, 256, 0, stream>>>(W, sqv, W16);
    pairwise_kernel<<<NBLK, 256, 0, stream>>>(W16, sqv, partA);
    pair_kernel<<<NPAIR_BLK, 256, 0, stream>>>(W16, pij, ii, jj, nb, a1p, a3p);
    final_kernel<<<1, 256, 0, stream>>>(partA, a1p, a3p, out);
}